// Round 4
// baseline (319.687 us; speedup 1.0000x reference)
//
#include <hip/hip_runtime.h>

typedef unsigned short u16;
typedef unsigned int u32;
typedef unsigned char u8;
typedef unsigned long long u64;

#define N_NODES 100000
#define N_EDGES 600000
#define D 128
#define NPG 1000
#define NGRAPH 100
#define MBW 3125          // mask words = ceil(100000/32)

#define CAP_SLOTS 65536   // CSR slots (expected ~29.4k)
#define CAP_L1    16384   // S1 nodes (expected ~4.9k)
#define CAP_L2    4096    // S2 nodes (expected ~700)
#define CAP_E2    16384   // edges into S2 (expected ~4.2k)
#define CAP_E3    4096    // edges into masters (expected ~600)

// ctrl slots
#define C_SLOT 0
#define C_L1   1
#define C_L2   2
#define C_E2   3
#define C_E3   4

__device__ __forceinline__ float bf2f(u16 u) {
  return __uint_as_float(((u32)u) << 16);
}
__device__ __forceinline__ u16 f2bf(float f) {
  u32 u = __float_as_uint(f);
  u32 r = (u + 0x7FFFu + ((u >> 16) & 1u)) >> 16;  // RNE
  return (u16)r;
}
__device__ __forceinline__ void fma4(float4& acc, float a, const float4 w) {
  acc.x = fmaf(a, w.x, acc.x);
  acc.y = fmaf(a, w.y, acc.y);
  acc.z = fmaf(a, w.z, acc.z);
  acc.w = fmaf(a, w.w, acc.w);
}
__device__ __forceinline__ float4 bf4(uint2 u) {
  return make_float4(bf2f((u16)(u.x & 0xFFFFu)), bf2f((u16)(u.x >> 16)),
                     bf2f((u16)(u.y & 0xFFFFu)), bf2f((u16)(u.y >> 16)));
}
__device__ __forceinline__ void add4(float4& a, const float4 b) {
  a.x += b.x; a.y += b.y; a.z += b.z; a.w += b.w;
}
__device__ __forceinline__ float4 shfl4(float4 v, int lane) {
  return make_float4(__shfl(v.x, lane, 32), __shfl(v.y, lane, 32),
                     __shfl(v.z, lane, 32), __shfl(v.w, lane, 32));
}
__device__ __forceinline__ int mbit(const u32* __restrict__ mb, int n) {
  return (mb[n >> 5] >> (n & 31)) & 1u;
}
__device__ __forceinline__ void mset(u32* __restrict__ mb, int n) {
  atomicOr(&mb[n >> 5], 1u << (n & 31));
}

// ---------------- cone construction (bitmask, int4-vectorized) ----------------

__global__ __launch_bounds__(256) void k_mark(u32* __restrict__ mb2) {
  int t = blockIdx.x * 256 + threadIdx.x;
  if (t < NGRAPH) mset(mb2, t * NPG);
}

// mb2 |= src of edges into masters
__global__ __launch_bounds__(256) void k_scan3(const int4* __restrict__ src4,
                                               const int4* __restrict__ dst4,
                                               u32* __restrict__ mb2) {
  int i = blockIdx.x * 256 + threadIdx.x;
  if (i >= N_EDGES / 4) return;
  int4 d = dst4[i], s = src4[i];
  if (d.x % NPG == 0) mset(mb2, s.x);
  if (d.y % NPG == 0) mset(mb2, s.y);
  if (d.z % NPG == 0) mset(mb2, s.z);
  if (d.w % NPG == 0) mset(mb2, s.w);
}

// mb1 |= src of edges into S2
__global__ __launch_bounds__(256) void k_scan2(const int4* __restrict__ src4,
                                               const int4* __restrict__ dst4,
                                               const u32* __restrict__ mb2,
                                               u32* __restrict__ mb1) {
  int i = blockIdx.x * 256 + threadIdx.x;
  if (i >= N_EDGES / 4) return;
  int4 d = dst4[i], s = src4[i];
  if (mbit(mb2, d.x)) mset(mb1, s.x);
  if (mbit(mb2, d.y)) mset(mb1, s.y);
  if (mbit(mb2, d.z)) mset(mb1, s.z);
  if (mbit(mb2, d.w)) mset(mb1, s.w);
}

// mb1 |= mb2  (S1 ⊇ S2)
__global__ __launch_bounds__(256) void k_or(u32* __restrict__ mb1,
                                            const u32* __restrict__ mb2) {
  int t = blockIdx.x * 256 + threadIdx.x;
  if (t < MBW) mb1[t] |= mb2[t];
}

// deg[d]++ for edges with dst in S1
__global__ __launch_bounds__(256) void k_scan1(const int4* __restrict__ dst4,
                                               const u32* __restrict__ mb1,
                                               int* __restrict__ deg) {
  int i = blockIdx.x * 256 + threadIdx.x;
  if (i >= N_EDGES / 4) return;
  int4 d = dst4[i];
  if (mbit(mb1, d.x)) atomicAdd(&deg[d.x], 1);
  if (mbit(mb1, d.y)) atomicAdd(&deg[d.y], 1);
  if (mbit(mb1, d.z)) atomicAdd(&deg[d.z], 1);
  if (mbit(mb1, d.w)) atomicAdd(&deg[d.w], 1);
}

// CSR segment allocation via wave-level prefix scan (1 atomic per wave);
// also builds L1/L2 node lists via ballot compaction.
__global__ __launch_bounds__(256) void k_alloc(const u32* __restrict__ mb1,
                                               const u32* __restrict__ mb2,
                                               const int* __restrict__ deg,
                                               int* __restrict__ offn,
                                               int* __restrict__ cur,
                                               int* __restrict__ L1,
                                               int* __restrict__ L2,
                                               int* __restrict__ ctrl) {
  int t = blockIdx.x * 256 + threadIdx.x;
  int lane = threadIdx.x & 63;
  bool inb = t < N_NODES;
  bool mk1 = inb && mbit(mb1, t);
  bool mk2 = inb && mbit(mb2, t);

  // wave prefix-scan of deg over marked lanes -> contiguous CSR ranges
  int v = mk1 ? deg[t] : 0;
  int incl = v;
#pragma unroll
  for (int o = 1; o < 64; o <<= 1) {
    int u = __shfl_up(incl, o, 64);
    if (lane >= o) incl += u;
  }
  int total = __shfl(incl, 63, 64);
  int sbase = 0;
  if (lane == 0 && total > 0) sbase = atomicAdd(&ctrl[C_SLOT], total);
  sbase = __shfl(sbase, 0, 64);
  int myoff = sbase + incl - v;
  if (mk1) { offn[t] = myoff; cur[t] = myoff; }

  // L1 list
  u64 bal = __ballot(mk1);
  int cnt = __popcll(bal);
  int pos = __popcll(bal & ((1ull << lane) - 1ull));
  int lbase = 0;
  if (lane == 0 && cnt > 0) lbase = atomicAdd(&ctrl[C_L1], cnt);
  lbase = __shfl(lbase, 0, 64);
  if (mk1 && lbase + pos < CAP_L1) L1[lbase + pos] = t;

  // L2 list
  u64 bal2 = __ballot(mk2);
  int cnt2 = __popcll(bal2);
  int pos2 = __popcll(bal2 & ((1ull << lane) - 1ull));
  int lbase2 = 0;
  if (lane == 0 && cnt2 > 0) lbase2 = atomicAdd(&ctrl[C_L2], cnt2);
  lbase2 = __shfl(lbase2, 0, 64);
  if (mk2 && lbase2 + pos2 < CAP_L2) L2[lbase2 + pos2] = t;
}

// scatter edges into CSR; emit E2/E3 packed lists {p, src, dst, e}
__global__ __launch_bounds__(256) void k_scatter(const int4* __restrict__ src4,
                                                 const int4* __restrict__ dst4,
                                                 const u32* __restrict__ mb1,
                                                 const u32* __restrict__ mb2,
                                                 int* __restrict__ cur,
                                                 int* __restrict__ csr_src,
                                                 int* __restrict__ csr_eid,
                                                 int4* __restrict__ E2,
                                                 int4* __restrict__ E3,
                                                 int* __restrict__ ctrl) {
  int i = blockIdx.x * 256 + threadIdx.x;
  if (i >= N_EDGES / 4) return;
  int4 dv = dst4[i], sv = src4[i];
  int ds[4] = {dv.x, dv.y, dv.z, dv.w};
  int ss[4] = {sv.x, sv.y, sv.z, sv.w};
#pragma unroll
  for (int j = 0; j < 4; ++j) {
    int d = ds[j];
    if (!mbit(mb1, d)) continue;
    int s = ss[j], e = i * 4 + j;
    int p = atomicAdd(&cur[d], 1);
    if (p < CAP_SLOTS) { csr_src[p] = s; csr_eid[p] = e; }
    if (mbit(mb2, d)) {
      int a = atomicAdd(&ctrl[C_E2], 1);
      if (a < CAP_E2) E2[a] = make_int4(p, s, d, e);
    }
    if (d % NPG == 0) {
      int b = atomicAdd(&ctrl[C_E3], 1);
      if (b < CAP_E3) E3[b] = make_int4(p, s, d, e);
    }
  }
}

// ---------------- compute ----------------
// fused node update: xout[n] = relu([x[n] | Σx[src] | Σea] @ [ws;wm] + bs + deg*bm)
// layer 1 (tok!=0, attr!=0): x rows = emb[tok[.]]; Σea = (Σattr)@w_proj + deg*b_proj
// layer 2 (tok==0): x rows = xin; Σea = Σ bf16 ea[p]
__global__ __launch_bounds__(256) void k_node(const int* __restrict__ tok,
                                              const float* __restrict__ emb,
                                              const float* __restrict__ xin,
                                              const float* __restrict__ attr,
                                              const float* __restrict__ wproj,
                                              const float* __restrict__ bproj,
                                              const u16* __restrict__ ea,
                                              const int* __restrict__ csr_src,
                                              const int* __restrict__ csr_eid,
                                              const int* __restrict__ offn,
                                              const int* __restrict__ cur,
                                              const float* __restrict__ ws,
                                              const float* __restrict__ bs,
                                              const float* __restrict__ wm,
                                              const float* __restrict__ bm,
                                              const int* __restrict__ L,
                                              const int* __restrict__ ctrl, int slot, int cap,
                                              float* __restrict__ xout) {
  int n_ = ctrl[slot];
  if (n_ > cap) n_ = cap;
  int sub = threadIdx.x >> 5, q = threadIdx.x & 31;
  const float4* wsa = (const float4*)ws;
  const float4* wmb = (const float4*)wm;
  for (int i = blockIdx.x * 8 + sub; i < n_; i += gridDim.x * 8) {
    int n = L[i];
    int o = offn[n], end = cur[n];
    float dgf = (float)(end - o);
    float4 sx = make_float4(0.f, 0.f, 0.f, 0.f);
    float4 se = make_float4(0.f, 0.f, 0.f, 0.f);
    if (tok) {
      float4 sa = make_float4(0.f, 0.f, 0.f, 0.f);
      for (int p = o; p < end; ++p) {
        int s = csr_src[p], e = csr_eid[p];
        add4(sx, ((const float4*)(emb + (size_t)tok[s] * D))[q]);
        add4(sa, ((const float4*)(attr + (size_t)e * 16))[q & 3]);
      }
      // se = (Σattr)@w_proj + deg*b_proj
      float4 bp = ((const float4*)bproj)[q];
      se = make_float4(bp.x * dgf, bp.y * dgf, bp.z * dgf, bp.w * dgf);
      const float4* wp = (const float4*)wproj;
#pragma unroll
      for (int k4 = 0; k4 < 4; ++k4) {
        float4 xv = shfl4(sa, k4);
        fma4(se, xv.x, wp[(k4 * 4 + 0) * 32 + q]);
        fma4(se, xv.y, wp[(k4 * 4 + 1) * 32 + q]);
        fma4(se, xv.z, wp[(k4 * 4 + 2) * 32 + q]);
        fma4(se, xv.w, wp[(k4 * 4 + 3) * 32 + q]);
      }
    } else {
      for (int p = o; p < end; ++p) {
        int s = csr_src[p];
        add4(sx, ((const float4*)(xin + (size_t)s * D))[q]);
        add4(se, bf4(((const uint2*)(ea + (size_t)p * D))[q]));
      }
    }
    const float* rown = tok ? (emb + (size_t)tok[n] * D) : (xin + (size_t)n * D);
    float4 xn = ((const float4*)rown)[q];
    float4 acc = ((const float4*)bs)[q];
#pragma unroll 4
    for (int k4 = 0; k4 < 32; ++k4) {   // x[n] @ ws
      float4 xv = shfl4(xn, k4);
      fma4(acc, xv.x, wsa[(k4 * 4 + 0) * 32 + q]);
      fma4(acc, xv.y, wsa[(k4 * 4 + 1) * 32 + q]);
      fma4(acc, xv.z, wsa[(k4 * 4 + 2) * 32 + q]);
      fma4(acc, xv.w, wsa[(k4 * 4 + 3) * 32 + q]);
    }
#pragma unroll 4
    for (int k4 = 0; k4 < 32; ++k4) {   // Σx_src @ wm[0:128]
      float4 xv = shfl4(sx, k4);
      fma4(acc, xv.x, wmb[(k4 * 4 + 0) * 32 + q]);
      fma4(acc, xv.y, wmb[(k4 * 4 + 1) * 32 + q]);
      fma4(acc, xv.z, wmb[(k4 * 4 + 2) * 32 + q]);
      fma4(acc, xv.w, wmb[(k4 * 4 + 3) * 32 + q]);
    }
#pragma unroll 4
    for (int k4 = 0; k4 < 32; ++k4) {   // Σea @ wm[128:256]
      float4 xv = shfl4(se, k4);
      fma4(acc, xv.x, wmb[(D + k4 * 4 + 0) * 32 + q]);
      fma4(acc, xv.y, wmb[(D + k4 * 4 + 1) * 32 + q]);
      fma4(acc, xv.z, wmb[(D + k4 * 4 + 2) * 32 + q]);
      fma4(acc, xv.w, wmb[(D + k4 * 4 + 3) * 32 + q]);
    }
    float4 bmv = ((const float4*)bm)[q];
    acc.x = fmaxf(fmaf(dgf, bmv.x, acc.x), 0.f);
    acc.y = fmaxf(fmaf(dgf, bmv.y, acc.y), 0.f);
    acc.z = fmaxf(fmaf(dgf, bmv.z, acc.z), 0.f);
    acc.w = fmaxf(fmaf(dgf, bmv.w, acc.w), 0.f);
    ((float4*)(xout + (size_t)n * D))[q] = acc;
  }
}

// edge update over packed list: ea[p] = relu([x_d | x_s | ev] @ we + be)
// layer 1 (tok!=0): x rows = emb[tok[.]]; ev = attr[e]@w_proj + b_proj
// layer 2: x rows = xin; ev = bf16 ea[p]
__global__ __launch_bounds__(256) void k_edge(const int* __restrict__ tok,
                                              const float* __restrict__ emb,
                                              const float* __restrict__ xin,
                                              const float* __restrict__ attr,
                                              const float* __restrict__ wproj,
                                              const float* __restrict__ bproj,
                                              u16* __restrict__ ea,
                                              const int4* __restrict__ EL,
                                              const int* __restrict__ ctrl, int slot, int cap,
                                              const float* __restrict__ we,
                                              const float* __restrict__ be) {
  int n_ = ctrl[slot];
  if (n_ > cap) n_ = cap;
  int sub = threadIdx.x >> 5, q = threadIdx.x & 31;
  const float4* w4 = (const float4*)we;
  for (int i = blockIdx.x * 8 + sub; i < n_; i += gridDim.x * 8) {
    int4 t = EL[i];
    int p = t.x, s = t.y, d = t.z, e = t.w;
    const float* rowd = tok ? (emb + (size_t)tok[d] * D) : (xin + (size_t)d * D);
    const float* rows = tok ? (emb + (size_t)tok[s] * D) : (xin + (size_t)s * D);
    float4 xi = ((const float4*)rowd)[q];
    float4 xj = ((const float4*)rows)[q];
    float4 ev;
    if (tok) {
      float4 av = ((const float4*)(attr + (size_t)e * 16))[q & 3];
      ev = ((const float4*)bproj)[q];
      const float4* wp = (const float4*)wproj;
#pragma unroll
      for (int k4 = 0; k4 < 4; ++k4) {
        float4 xv = shfl4(av, k4);
        fma4(ev, xv.x, wp[(k4 * 4 + 0) * 32 + q]);
        fma4(ev, xv.y, wp[(k4 * 4 + 1) * 32 + q]);
        fma4(ev, xv.z, wp[(k4 * 4 + 2) * 32 + q]);
        fma4(ev, xv.w, wp[(k4 * 4 + 3) * 32 + q]);
      }
    } else {
      ev = bf4(((const uint2*)(ea + (size_t)p * D))[q]);
    }
    float4 acc = ((const float4*)be)[q];
#pragma unroll 4
    for (int k4 = 0; k4 < 32; ++k4) {
      float4 xv = shfl4(xi, k4);
      fma4(acc, xv.x, w4[(k4 * 4 + 0) * 32 + q]);
      fma4(acc, xv.y, w4[(k4 * 4 + 1) * 32 + q]);
      fma4(acc, xv.z, w4[(k4 * 4 + 2) * 32 + q]);
      fma4(acc, xv.w, w4[(k4 * 4 + 3) * 32 + q]);
    }
#pragma unroll 4
    for (int k4 = 0; k4 < 32; ++k4) {
      float4 xv = shfl4(xj, k4);
      fma4(acc, xv.x, w4[(D + k4 * 4 + 0) * 32 + q]);
      fma4(acc, xv.y, w4[(D + k4 * 4 + 1) * 32 + q]);
      fma4(acc, xv.z, w4[(D + k4 * 4 + 2) * 32 + q]);
      fma4(acc, xv.w, w4[(D + k4 * 4 + 3) * 32 + q]);
    }
#pragma unroll 4
    for (int k4 = 0; k4 < 32; ++k4) {
      float4 xv = shfl4(ev, k4);
      fma4(acc, xv.x, w4[(2 * D + k4 * 4 + 0) * 32 + q]);
      fma4(acc, xv.y, w4[(2 * D + k4 * 4 + 1) * 32 + q]);
      fma4(acc, xv.z, w4[(2 * D + k4 * 4 + 2) * 32 + q]);
      fma4(acc, xv.w, w4[(2 * D + k4 * 4 + 3) * 32 + q]);
    }
    acc.x = fmaxf(acc.x, 0.f);
    acc.y = fmaxf(acc.y, 0.f);
    acc.z = fmaxf(acc.z, 0.f);
    acc.w = fmaxf(acc.w, 0.f);
    u32 p0 = (u32)f2bf(acc.x) | ((u32)f2bf(acc.y) << 16);
    u32 p1 = (u32)f2bf(acc.z) | ((u32)f2bf(acc.w) << 16);
    ((uint2*)(ea + (size_t)p * D))[q] = make_uint2(p0, p1);
  }
}

// layer 3 masters only: out[g] = [x2[m] | Σx2[src] | Σea2] @ [ws;wm] + bs + deg*bm
__global__ __launch_bounds__(256) void k_out(const float* __restrict__ x2,
                                             const u16* __restrict__ ea,
                                             const int* __restrict__ csr_src,
                                             const int* __restrict__ offn,
                                             const int* __restrict__ cur,
                                             const float* __restrict__ ws,
                                             const float* __restrict__ bs,
                                             const float* __restrict__ wm,
                                             const float* __restrict__ bm,
                                             float* __restrict__ out) {
  int t = blockIdx.x * 256 + threadIdx.x;
  int g = t >> 5;
  if (g >= NGRAPH) return;
  int q = t & 31;
  int n = g * NPG;
  int o = offn[n], end = cur[n];
  float dgf = (float)(end - o);
  float4 sx = make_float4(0.f, 0.f, 0.f, 0.f);
  float4 se = make_float4(0.f, 0.f, 0.f, 0.f);
  for (int p = o; p < end; ++p) {
    int s = csr_src[p];
    add4(sx, ((const float4*)(x2 + (size_t)s * D))[q]);
    add4(se, bf4(((const uint2*)(ea + (size_t)p * D))[q]));
  }
  float4 xn = ((const float4*)(x2 + (size_t)n * D))[q];
  float4 acc = ((const float4*)bs)[q];
  const float4* wsa = (const float4*)ws;
  const float4* wmb = (const float4*)wm;
#pragma unroll 4
  for (int k4 = 0; k4 < 32; ++k4) {
    float4 xv = shfl4(xn, k4);
    fma4(acc, xv.x, wsa[(k4 * 4 + 0) * 32 + q]);
    fma4(acc, xv.y, wsa[(k4 * 4 + 1) * 32 + q]);
    fma4(acc, xv.z, wsa[(k4 * 4 + 2) * 32 + q]);
    fma4(acc, xv.w, wsa[(k4 * 4 + 3) * 32 + q]);
  }
#pragma unroll 4
  for (int k4 = 0; k4 < 32; ++k4) {
    float4 xv = shfl4(sx, k4);
    fma4(acc, xv.x, wmb[(k4 * 4 + 0) * 32 + q]);
    fma4(acc, xv.y, wmb[(k4 * 4 + 1) * 32 + q]);
    fma4(acc, xv.z, wmb[(k4 * 4 + 2) * 32 + q]);
    fma4(acc, xv.w, wmb[(k4 * 4 + 3) * 32 + q]);
  }
#pragma unroll 4
  for (int k4 = 0; k4 < 32; ++k4) {
    float4 xv = shfl4(se, k4);
    fma4(acc, xv.x, wmb[(D + k4 * 4 + 0) * 32 + q]);
    fma4(acc, xv.y, wmb[(D + k4 * 4 + 1) * 32 + q]);
    fma4(acc, xv.z, wmb[(D + k4 * 4 + 2) * 32 + q]);
    fma4(acc, xv.w, wmb[(D + k4 * 4 + 3) * 32 + q]);
  }
  float4 bmv = ((const float4*)bm)[q];
  acc.x = fmaf(dgf, bmv.x, acc.x);
  acc.y = fmaf(dgf, bmv.y, acc.y);
  acc.z = fmaf(dgf, bmv.z, acc.z);
  acc.w = fmaf(dgf, bmv.w, acc.w);
  ((float4*)(out + (size_t)g * D))[q] = acc;
}

extern "C" void kernel_launch(void* const* d_in, const int* in_sizes, int n_in,
                              void* d_out, int out_size, void* d_ws, size_t ws_size,
                              hipStream_t stream) {
  const int* tok = (const int*)d_in[0];
  const int* eidx = (const int*)d_in[1];
  const int4* src4 = (const int4*)eidx;
  const int4* dst4 = (const int4*)(eidx + N_EDGES);
  const float* attr = (const float*)d_in[2];
  const float* emb = (const float*)d_in[4];
  const float* w_proj = (const float*)d_in[5];
  const float* b_proj = (const float*)d_in[6];
  const float *ws_[3], *bs_[3], *wm_[3], *bm_[3], *we_[3], *be_[3];
  for (int i = 0; i < 3; ++i) {
    ws_[i] = (const float*)d_in[7 + 6 * i];
    bs_[i] = (const float*)d_in[8 + 6 * i];
    wm_[i] = (const float*)d_in[9 + 6 * i];
    bm_[i] = (const float*)d_in[10 + 6 * i];
    we_[i] = (const float*)d_in[11 + 6 * i];
    be_[i] = (const float*)d_in[12 + 6 * i];
  }
  float* out = (float*)d_out;

  // ---- workspace layout ----
  char* base = (char*)d_ws;
  size_t o = 0;
  int* ctrl = (int*)(base + o); o += 256;
  int* deg  = (int*)(base + o); o += (size_t)N_NODES * 4;
  u32* mb1  = (u32*)(base + o); o += 12512;
  u32* mb2  = (u32*)(base + o); o += 12512;
  size_t zero_bytes = o;  // ctrl + deg + masks must start at 0 each call
  int* offn = (int*)(base + o); o += (size_t)N_NODES * 4;
  int* cur  = (int*)(base + o); o += (size_t)N_NODES * 4;
  int* csr_src = (int*)(base + o); o += (size_t)CAP_SLOTS * 4;
  int* csr_eid = (int*)(base + o); o += (size_t)CAP_SLOTS * 4;
  o = (o + 15) & ~(size_t)15;
  int4* E2 = (int4*)(base + o); o += (size_t)CAP_E2 * 16;
  int4* E3 = (int4*)(base + o); o += (size_t)CAP_E3 * 16;
  int* L1 = (int*)(base + o); o += (size_t)CAP_L1 * 4;
  int* L2 = (int*)(base + o); o += (size_t)CAP_L2 * 4;
  o = (o + 511) & ~(size_t)511;
  float* x1 = (float*)(base + o); o += (size_t)N_NODES * D * 4;
  float* x2 = (float*)(base + o); o += (size_t)N_NODES * D * 4;
  u16* ea = (u16*)(base + o); o += (size_t)CAP_SLOTS * D * 2;

  hipMemsetAsync(d_ws, 0, zero_bytes, stream);

  dim3 B(256);
  const int EG4 = (N_EDGES / 4 + 255) / 256;  // 586
  const int NG = (N_NODES + 255) / 256;       // 391

  k_mark<<<1, B, 0, stream>>>(mb2);
  k_scan3<<<EG4, B, 0, stream>>>(src4, dst4, mb2);
  k_scan2<<<EG4, B, 0, stream>>>(src4, dst4, mb2, mb1);
  k_or<<<(MBW + 255) / 256, B, 0, stream>>>(mb1, mb2);
  k_scan1<<<EG4, B, 0, stream>>>(dst4, mb1, deg);
  k_alloc<<<NG, B, 0, stream>>>(mb1, mb2, deg, offn, cur, L1, L2, ctrl);
  k_scatter<<<EG4, B, 0, stream>>>(src4, dst4, mb1, mb2, cur,
                                   csr_src, csr_eid, E2, E3, ctrl);

  // layer 1: x1 = relu(conv1(emb[tok], attr-proj)) on S1; ea1 on E2 (proj inline)
  k_node<<<768, B, 0, stream>>>(tok, emb, nullptr, attr, w_proj, b_proj, ea,
                                csr_src, csr_eid, offn, cur,
                                ws_[0], bs_[0], wm_[0], bm_[0],
                                L1, ctrl, C_L1, CAP_L1, x1);
  k_edge<<<512, B, 0, stream>>>(tok, emb, nullptr, attr, w_proj, b_proj, ea,
                                E2, ctrl, C_E2, CAP_E2, we_[0], be_[0]);

  // layer 2: x2 = relu(conv2(x1, ea1)) on S2; ea2 on E3
  k_node<<<128, B, 0, stream>>>(nullptr, nullptr, x1, nullptr, nullptr, nullptr, ea,
                                csr_src, csr_eid, offn, cur,
                                ws_[1], bs_[1], wm_[1], bm_[1],
                                L2, ctrl, C_L2, CAP_L2, x2);
  k_edge<<<128, B, 0, stream>>>(nullptr, nullptr, x1, nullptr, nullptr, nullptr, ea,
                                E3, ctrl, C_E3, CAP_E3, we_[1], be_[1]);

  // layer 3: masters only, no relu, e_out discarded
  k_out<<<13, B, 0, stream>>>(x2, ea, csr_src, offn, cur,
                              ws_[2], bs_[2], wm_[2], bm_[2], out);
}